// Round 1
// baseline (1398.256 us; speedup 1.0000x reference)
//
#include <hip/hip_runtime.h>

#define DEVI __device__ __forceinline__

static constexpr int Bb = 64;
static constexpr int Ss = 3000;
static constexpr int Mm = Bb * Ss;      // 192000
static constexpr int NCH = 12;          // sequence chunks
static constexpr int CLEN = 250;        // chunk length
static constexpr int WARM = 64;         // scan warmup steps
static constexpr int RWARM = 32;        // rnn warmup steps

DEVI float fast_tanh(float x) {
    float e = __expf(2.0f * x);
    return 1.0f - 2.0f / (e + 1.0f);
}
DEVI float fast_sigmoid(float x) {
    return 1.0f / (1.0f + __expf(-x));
}

// ---------------- RNN (hidden=4), chunked with warmup ----------------
__global__ void rnn_kernel(const float* __restrict__ x, const float* __restrict__ wih,
                           const float* __restrict__ whh, const float* __restrict__ bih,
                           const float* __restrict__ bhh, float* __restrict__ hout) {
    int id = blockIdx.x * blockDim.x + threadIdx.x;
    if (id >= Bb * NCH) return;
    int b = id / NCH, ck = id % NCH;
    float w[4][4], wi[4], bc[4];
#pragma unroll
    for (int j = 0; j < 4; ++j) {
        wi[j] = wih[j];
        bc[j] = bih[j] + bhh[j];
#pragma unroll
        for (int i = 0; i < 4; ++i) w[j][i] = whh[j * 4 + i];
    }
    float h0 = 0.f, h1 = 0.f, h2 = 0.f, h3 = 0.f;
    int sc = ck * CLEN;
    int sb = sc - (ck ? RWARM : 0);
    for (int s = sb; s < sc + CLEN; ++s) {
        float xv = x[b * Ss + s];
        float n0 = fast_tanh(fmaf(xv, wi[0], bc[0]) + w[0][0]*h0 + w[0][1]*h1 + w[0][2]*h2 + w[0][3]*h3);
        float n1 = fast_tanh(fmaf(xv, wi[1], bc[1]) + w[1][0]*h0 + w[1][1]*h1 + w[1][2]*h2 + w[1][3]*h3);
        float n2 = fast_tanh(fmaf(xv, wi[2], bc[2]) + w[2][0]*h0 + w[2][1]*h1 + w[2][2]*h2 + w[2][3]*h3);
        float n3 = fast_tanh(fmaf(xv, wi[3], bc[3]) + w[3][0]*h0 + w[3][1]*h1 + w[3][2]*h2 + w[3][3]*h3);
        h0 = n0; h1 = n1; h2 = n2; h3 = n3;
        if (s >= sc) {
            float4 v = make_float4(h0, h1, h2, h3);
            *(float4*)&hout[(size_t)(b * Ss + s) * 4] = v;
        }
    }
}

// ---------------- QRNN GEMM: zf = act(A @ Wcols + b) ----------------
// A: (M,K).  Writes compact ZF (M, Wout) where cols [0,Hg)=tanh(z), [Hg,2Hg)=sigmoid(f).
// Weight column mapping: j<Hg -> z0+j ; else f0+(j-Hg).
template <int K>
__global__ __launch_bounds__(256) void qrnn_gemm(const float* __restrict__ A,
                                                 const float* __restrict__ W,
                                                 const float* __restrict__ bias,
                                                 float* __restrict__ ZF,
                                                 int Nfull, int Wout, int Hg, int z0, int f0) {
    constexpr int BM = 64, BN = 64;
    constexpr int BK = (K < 32) ? K : 32;
    __shared__ float As[BK][BM + 4];
    __shared__ float Bs[BK][BN];
    const int tid = threadIdx.x;
    const int tx = tid % 16, ty = tid / 16;
    const int m0 = blockIdx.x * BM;
    const int n0 = blockIdx.y * BN;
    float acc[4][4] = {};

    for (int k0 = 0; k0 < K; k0 += BK) {
        constexpr int KQ = BK / 4;
        constexpr int AV = BM * KQ;
        for (int v = tid; v < AV; v += 256) {
            int m = v / KQ, kq = v % KQ;
            float4 av = *(const float4*)&A[(size_t)(m0 + m) * K + k0 + kq * 4];
            As[kq * 4 + 0][m] = av.x;
            As[kq * 4 + 1][m] = av.y;
            As[kq * 4 + 2][m] = av.z;
            As[kq * 4 + 3][m] = av.w;
        }
        constexpr int BV = BK * 16;
        for (int v = tid; v < BV; v += 256) {
            int ki = v / 16, nq = v % 16;
            int j = n0 + nq * 4;
            float4 bv = make_float4(0.f, 0.f, 0.f, 0.f);
            if (j < Wout) {
                int wc = (j < Hg) ? (z0 + j) : (f0 + (j - Hg));
                bv = *(const float4*)&W[(size_t)(k0 + ki) * Nfull + wc];
            }
            *(float4*)&Bs[ki][nq * 4] = bv;
        }
        __syncthreads();
#pragma unroll
        for (int kk = 0; kk < BK; ++kk) {
            float a[4];
#pragma unroll
            for (int i = 0; i < 4; ++i) a[i] = As[kk][ty * 4 + i];
            float4 bv = *(const float4*)&Bs[kk][tx * 4];
            float bb[4] = {bv.x, bv.y, bv.z, bv.w};
#pragma unroll
            for (int i = 0; i < 4; ++i)
#pragma unroll
                for (int j = 0; j < 4; ++j) acc[i][j] = fmaf(a[i], bb[j], acc[i][j]);
        }
        __syncthreads();
    }
    // epilogue: bias + activation, vector store
    int jb = n0 + tx * 4;
    if (jb < Wout) {
        bool isz = jb < Hg;
#pragma unroll
        for (int i = 0; i < 4; ++i) {
            int gm = m0 + ty * 4 + i;
            float o[4];
#pragma unroll
            for (int jj = 0; jj < 4; ++jj) {
                int j = jb + jj;
                int wc = isz ? (z0 + j) : (f0 + (j - Hg));
                float v = acc[i][jj] + bias[wc];
                o[jj] = isz ? fast_tanh(v) : fast_sigmoid(v);
            }
            float4 ov = make_float4(o[0], o[1], o[2], o[3]);
            *(float4*)&ZF[(size_t)gm * Wout + jb] = ov;
        }
    }
}

// ---------------- fo-pool scan (layers 1-4), chunked with warmup ----------------
__global__ void scan_kernel(const float* __restrict__ zf, float* __restrict__ hout,
                            int Hg, int W2, int Hfull, int ch0) {
    int id = blockIdx.x * blockDim.x + threadIdx.x;
    int total = Bb * NCH * Hg;
    if (id >= total) return;
    int c = id % Hg;
    int p = id / Hg;
    int b = p / NCH, ck = p % NCH;
    int sc = ck * CLEN;
    float h = 0.f;
    if (ck) {
#pragma unroll 4
        for (int s = sc - WARM; s < sc; ++s) {
            size_t base = (size_t)(b * Ss + s) * W2;
            float z = zf[base + c], f = zf[base + Hg + c];
            h = fmaf(f, h - z, z);
        }
    }
#pragma unroll 5
    for (int s = sc; s < sc + CLEN; ++s) {
        size_t base = (size_t)(b * Ss + s) * W2;
        float z = zf[base + c], f = zf[base + Hg + c];
        h = fmaf(f, h - z, z);
        hout[(size_t)(b * Ss + s) * Hfull + ch0 + c] = h;
    }
}

// ---------------- L5 scan fused with mean-pool over channels ----------------
template <int HG>
__global__ void scan_pool_kernel(const float* __restrict__ zf, float* __restrict__ pooled,
                                 int initflag) {
    constexpr int W2 = 2 * HG;
    constexpr int WIN = 50;
    __shared__ float tile[WIN][HG + 1];
    int b = blockIdx.x, ck = blockIdx.y;
    int c = threadIdx.x;
    int sc = ck * CLEN;
    float h = 0.f;
    if (ck) {
#pragma unroll 4
        for (int s = sc - WARM; s < sc; ++s) {
            size_t base = (size_t)(b * Ss + s) * W2;
            float z = zf[base + c], f = zf[base + HG + c];
            h = fmaf(f, h - z, z);
        }
    }
    for (int w0 = 0; w0 < CLEN; w0 += WIN) {
#pragma unroll 5
        for (int r = 0; r < WIN; ++r) {
            size_t base = (size_t)(b * Ss + sc + w0 + r) * W2;
            float z = zf[base + c], f = zf[base + HG + c];
            h = fmaf(f, h - z, z);
            tile[r][c] = h;
        }
        __syncthreads();
#pragma unroll
        for (int stride = HG >> 1; stride >= 1; stride >>= 1) {
            for (int idx = c; idx < WIN * stride; idx += HG) {
                int r = idx / stride, cc = idx % stride;
                tile[r][cc] += tile[r][cc + stride];
            }
            __syncthreads();
        }
        if (c < WIN) {
            size_t po = (size_t)b * Ss + sc + w0 + c;
            float v = tile[c][0] * (1.f / 256.f);
            if (initflag) pooled[po] = v;
            else pooled[po] += v;
        }
        __syncthreads();
    }
}

// ---------------- MLP1: (64,3000)@(3000,1024), split-K partials ----------------
__global__ __launch_bounds__(256) void mlp1_kernel(const float* __restrict__ xp,
                                                   const float* __restrict__ w1,
                                                   float* __restrict__ parts) {
    const int n0 = blockIdx.x * 64;
    const int ks = blockIdx.y;         // 12 k-splits of 250
    const int kbeg = ks * 250;
    const int nl = threadIdx.x % 64, mg = threadIdx.x / 64;
    __shared__ float xs[50][68];
    float acc[16] = {};
    for (int kc = 0; kc < 5; ++kc) {
        int k0 = kbeg + kc * 50;
        __syncthreads();
        for (int idx = threadIdx.x; idx < 64 * 50; idx += 256) {
            int r = idx / 50, cc = idx % 50;
            xs[cc][r] = xp[r * Ss + k0 + cc];
        }
        __syncthreads();
#pragma unroll 5
        for (int kk = 0; kk < 50; ++kk) {
            float wv = w1[(size_t)(k0 + kk) * 1024 + n0 + nl];
#pragma unroll
            for (int q = 0; q < 4; ++q) {
                float4 xv = *(const float4*)&xs[kk][mg * 16 + q * 4];
                acc[q * 4 + 0] = fmaf(xv.x, wv, acc[q * 4 + 0]);
                acc[q * 4 + 1] = fmaf(xv.y, wv, acc[q * 4 + 1]);
                acc[q * 4 + 2] = fmaf(xv.z, wv, acc[q * 4 + 2]);
                acc[q * 4 + 3] = fmaf(xv.w, wv, acc[q * 4 + 3]);
            }
        }
    }
#pragma unroll
    for (int i = 0; i < 16; ++i) {
        int m = mg * 16 + i;
        parts[((size_t)ks * 64 + m) * 1024 + n0 + nl] = acc[i];
    }
}

__global__ void mlp1_reduce(const float* __restrict__ parts, const float* __restrict__ b1,
                            float* __restrict__ h1) {
    int id = blockIdx.x * 256 + threadIdx.x;   // 65536
    int n = id % 1024, m = id / 1024;
    float s = b1[n];
#pragma unroll
    for (int ks = 0; ks < 12; ++ks) s += parts[((size_t)ks * 64 + m) * 1024 + n];
    h1[id] = fmaxf(s, 0.f);
}

__global__ void mlp2_kernel(const float* __restrict__ h1, const float* __restrict__ w2,
                            const float* __restrict__ b2, float* __restrict__ h2) {
    int m = blockIdx.x, n = threadIdx.x;   // 64 blocks x 128
    float acc = 0.f;
#pragma unroll 8
    for (int k = 0; k < 1024; ++k) acc = fmaf(h1[m * 1024 + k], w2[k * 128 + n], acc);
    h2[m * 128 + n] = fmaxf(acc + b2[n], 0.f);
}

__global__ void mlp3_kernel(const float* __restrict__ h2, const float* __restrict__ w3,
                            const float* __restrict__ b3, float* __restrict__ out) {
    int t = threadIdx.x;
    if (t >= 640) return;
    int m = t / 10, n = t % 10;
    float acc = 0.f;
#pragma unroll
    for (int k = 0; k < 128; ++k) acc = fmaf(h2[m * 128 + k], w3[k * 10 + n], acc);
    out[t] = fmaxf(acc + b3[n], 0.f);
}

// ---------------- launcher ----------------
extern "C" void kernel_launch(void* const* d_in, const int* in_sizes, int n_in,
                              void* d_out, int out_size, void* d_ws, size_t ws_size,
                              hipStream_t stream) {
    const float* x   = (const float*)d_in[0];
    const float* wih = (const float*)d_in[1];
    const float* whh = (const float*)d_in[2];
    const float* bih = (const float*)d_in[3];
    const float* bhh = (const float*)d_in[4];
    const float* qw[5] = {(const float*)d_in[5], (const float*)d_in[7], (const float*)d_in[9],
                          (const float*)d_in[11], (const float*)d_in[13]};
    const float* qb[5] = {(const float*)d_in[6], (const float*)d_in[8], (const float*)d_in[10],
                          (const float*)d_in[12], (const float*)d_in[14]};
    const float* w1 = (const float*)d_in[15];
    const float* b1 = (const float*)d_in[16];
    const float* w2 = (const float*)d_in[17];
    const float* b2 = (const float*)d_in[18];
    const float* w3 = (const float*)d_in[19];
    const float* b3 = (const float*)d_in[20];
    float* out = (float*)d_out;

    const size_t hA_sz = (size_t)Mm * 128 * 4;   // 98.3 MB
    const size_t hB_sz = (size_t)Mm * 64 * 4;    // 49.2 MB
    const size_t pooled_sz = (size_t)Bb * Ss * 4;
    const size_t parts_sz = 12ull * 64 * 1024 * 4;
    const size_t h1_sz = 64ull * 1024 * 4;
    const size_t h2_sz = 64ull * 128 * 4;
    const size_t tail = pooled_sz + parts_sz + h1_sz + h2_sz;

    // column-group splits per layer (keeps zf buffer within ws)
    int G[5] = {1, 1, 1, 1, 2};
    size_t zf_sz = (size_t)Mm * 256 * 4;                       // 196.6 MB
    if (ws_size < hA_sz + hB_sz + zf_sz + tail) {
        G[3] = 2; G[4] = 4; zf_sz = (size_t)Mm * 128 * 4;      // 98.3 MB
    }
    if (ws_size < hA_sz + hB_sz + zf_sz + tail) {
        G[2] = 2; G[3] = 4; G[4] = 8; zf_sz = (size_t)Mm * 64 * 4;
    }

    char* ws = (char*)d_ws;
    float* hA = (float*)ws;
    float* hB = (float*)(ws + hA_sz);
    float* zfb = (float*)(ws + hA_sz + hB_sz);
    float* pooled = (float*)(ws + hA_sz + hB_sz + zf_sz);
    float* parts = (float*)(ws + hA_sz + hB_sz + zf_sz + pooled_sz);
    float* h1m = (float*)(ws + hA_sz + hB_sz + zf_sz + pooled_sz + parts_sz);
    float* h2m = (float*)(ws + hA_sz + hB_sz + zf_sz + pooled_sz + parts_sz + h1_sz);

    rnn_kernel<<<3, 256, 0, stream>>>(x, wih, whh, bih, bhh, hA);

    const int Hs[5] = {16, 32, 64, 128, 256};
    float* hcur = hA;
    float* hnext = hB;
    for (int L = 0; L < 5; ++L) {
        int H = Hs[L], g = G[L], Hg = H / g, Wout = 2 * Hg, Nfull = 2 * H;
        for (int gi = 0; gi < g; ++gi) {
            int z0 = gi * Hg, f0 = H + gi * Hg;
            dim3 grid(Mm / 64, (Wout + 63) / 64);
            switch (L) {
                case 0: qrnn_gemm<4><<<grid, 256, 0, stream>>>(hcur, qw[L], qb[L], zfb, Nfull, Wout, Hg, z0, f0); break;
                case 1: qrnn_gemm<16><<<grid, 256, 0, stream>>>(hcur, qw[L], qb[L], zfb, Nfull, Wout, Hg, z0, f0); break;
                case 2: qrnn_gemm<32><<<grid, 256, 0, stream>>>(hcur, qw[L], qb[L], zfb, Nfull, Wout, Hg, z0, f0); break;
                case 3: qrnn_gemm<64><<<grid, 256, 0, stream>>>(hcur, qw[L], qb[L], zfb, Nfull, Wout, Hg, z0, f0); break;
                case 4: qrnn_gemm<128><<<grid, 256, 0, stream>>>(hcur, qw[L], qb[L], zfb, Nfull, Wout, Hg, z0, f0); break;
            }
            if (L < 4) {
                int total = Bb * NCH * Hg;
                scan_kernel<<<(total + 255) / 256, 256, 0, stream>>>(zfb, hnext, Hg, Wout, H, z0);
            } else {
                dim3 g2(Bb, NCH);
                if (Hg == 128)      scan_pool_kernel<128><<<g2, 128, 0, stream>>>(zfb, pooled, gi == 0);
                else if (Hg == 64)  scan_pool_kernel<64><<<g2, 64, 0, stream>>>(zfb, pooled, gi == 0);
                else                scan_pool_kernel<32><<<g2, 32, 0, stream>>>(zfb, pooled, gi == 0);
            }
        }
        if (L < 4) { float* t = hcur; hcur = hnext; hnext = t; }
    }

    mlp1_kernel<<<dim3(16, 12), 256, 0, stream>>>(pooled, w1, parts);
    mlp1_reduce<<<256, 256, 0, stream>>>(parts, b1, h1m);
    mlp2_kernel<<<64, 128, 0, stream>>>(h1m, w2, b2, h2m);
    mlp3_kernel<<<1, 640, 0, stream>>>(h2m, w3, b3, out);
    (void)in_sizes; (void)n_in; (void)out_size;
}